// Round 1
// baseline (169.861 us; speedup 1.0000x reference)
//
#include <hip/hip_runtime.h>

#define BDIM 128
#define CDIM 512
#define LIN  720
#define LOUT 336
#define BK   32
#define NSTAGES 23          // ceil(720/32): last stage half zero-padded
#define NTHREADS 768        // 12 waves: 4 (M) x 3 (N)

typedef short v8s __attribute__((ext_vector_type(8)));  // 8 bf16 (4 VGPR)
typedef float v4f __attribute__((ext_vector_type(4)));  // MFMA acc

__device__ __forceinline__ unsigned short f2bf(float f) {
    // round-to-nearest-even fp32 -> bf16 (inputs are finite randoms; no NaN path)
    unsigned int u = __builtin_bit_cast(unsigned int, f);
    u += 0x7fffu + ((u >> 16) & 1u);
    return (unsigned short)(u >> 16);
}

__global__ __launch_bounds__(NTHREADS, 3)
void grouped_linear_kernel(const float* __restrict__ x,
                           const float* __restrict__ W,
                           const float* __restrict__ bias,
                           float* __restrict__ out)
{
    const int c    = blockIdx.x;
    const int tid  = threadIdx.x;
    const int lane = tid & 63;
    const int wave = tid >> 6;
    const int wr   = wave / 3;   // 0..3 -> rows wr*32 .. +31
    const int wc   = wave % 3;   // 0..2 -> cols wc*112 .. +111

    // K-octet-subtiled layouts: [oct][outer][8 bf16 along k] -> frag reads are
    // contiguous ds_read_b128, consecutive lanes hit consecutive 16B slots.
    __shared__ unsigned short Alds[4 * BDIM * 8];   // x tile:  [oct][row][k7]
    __shared__ unsigned short Blds[4 * LOUT * 8];   // W^T tile:[oct][col][k7]

    const float* xg = x + (size_t)c * LIN;              // + row*CDIM*LIN + k
    const float* Wg = W + (size_t)c * LIN * LOUT;       // + k*LOUT + n

    // ---- staging task decomposition (fixed per thread) ----
    // A: 128 rows x 8 float4-chunks = 1024 tasks
    const int rowA0 = tid >> 3, kqA0 = tid & 7;
    const int tA1   = tid + NTHREADS;
    const int rowA1 = tA1 >> 3, kqA1 = tA1 & 7;
    const bool hasA1 = (tA1 < 1024);
    // B: 336 cols x 4 k-octets = 1344 tasks (transpose on the write path)
    const int nB0 = tid % LOUT, oB0 = tid / LOUT;
    const int tB1 = tid + NTHREADS;
    const int nB1 = tB1 % LOUT, oB1 = tB1 / LOUT;
    const bool hasB1 = (tB1 < 1344);

    // LDS write offsets (ushort element index)
    const int offA0 = ((kqA0 >> 1) * BDIM + rowA0) * 8 + (kqA0 & 1) * 4;
    const int offA1 = ((kqA1 >> 1) * BDIM + rowA1) * 8 + (kqA1 & 1) * 4;
    const int offB0 = (oB0 * LOUT + nB0) * 8;
    const int offB1 = (oB1 * LOUT + nB1) * 8;

    // fragment read bases: lane l -> outer = (l&15), k-octet = (l>>4)
    const int aBase = ((lane >> 4) * BDIM + wr * 32 + (lane & 15)) * 8;
    const int bBase = ((lane >> 4) * LOUT + wc * 112 + (lane & 15)) * 8;

    float a0[4], a1[4], b0[8], b1[8];

    v4f acc[2][7];
    #pragma unroll
    for (int m = 0; m < 2; ++m)
        #pragma unroll
        for (int n = 0; n < 7; ++n)
            acc[m][n] = (v4f){0.f, 0.f, 0.f, 0.f};

#define LOAD_STAGE(KS)                                                          \
    {                                                                           \
        const int kA0 = (KS) + kqA0 * 4;                                        \
        if (kA0 < LIN) {                                                        \
            const float4 v = *reinterpret_cast<const float4*>(                  \
                xg + (size_t)rowA0 * (CDIM * LIN) + kA0);                       \
            a0[0] = v.x; a0[1] = v.y; a0[2] = v.z; a0[3] = v.w;                 \
        } else { a0[0] = a0[1] = a0[2] = a0[3] = 0.f; }                         \
        if (hasA1) {                                                            \
            const int kA1 = (KS) + kqA1 * 4;                                    \
            if (kA1 < LIN) {                                                    \
                const float4 v = *reinterpret_cast<const float4*>(              \
                    xg + (size_t)rowA1 * (CDIM * LIN) + kA1);                   \
                a1[0] = v.x; a1[1] = v.y; a1[2] = v.z; a1[3] = v.w;             \
            } else { a1[0] = a1[1] = a1[2] = a1[3] = 0.f; }                     \
        }                                                                       \
        const int kB0 = (KS) + oB0 * 8;                                         \
        if (kB0 < LIN) {                                                        \
            const float* p = Wg + (size_t)kB0 * LOUT + nB0;                     \
            _Pragma("unroll")                                                   \
            for (int j = 0; j < 8; ++j) b0[j] = p[(size_t)j * LOUT];            \
        } else {                                                                \
            _Pragma("unroll")                                                   \
            for (int j = 0; j < 8; ++j) b0[j] = 0.f;                            \
        }                                                                       \
        if (hasB1) {                                                            \
            const int kB1 = (KS) + oB1 * 8;                                     \
            if (kB1 < LIN) {                                                    \
                const float* p = Wg + (size_t)kB1 * LOUT + nB1;                 \
                _Pragma("unroll")                                               \
                for (int j = 0; j < 8; ++j) b1[j] = p[(size_t)j * LOUT];        \
            } else {                                                            \
                _Pragma("unroll")                                               \
                for (int j = 0; j < 8; ++j) b1[j] = 0.f;                        \
            }                                                                   \
        }                                                                       \
    }

#define WRITE_STAGE()                                                           \
    {                                                                           \
        uint2 wa;                                                               \
        wa.x = (unsigned)f2bf(a0[0]) | ((unsigned)f2bf(a0[1]) << 16);           \
        wa.y = (unsigned)f2bf(a0[2]) | ((unsigned)f2bf(a0[3]) << 16);           \
        *reinterpret_cast<uint2*>(&Alds[offA0]) = wa;                           \
        if (hasA1) {                                                            \
            uint2 wb;                                                           \
            wb.x = (unsigned)f2bf(a1[0]) | ((unsigned)f2bf(a1[1]) << 16);       \
            wb.y = (unsigned)f2bf(a1[2]) | ((unsigned)f2bf(a1[3]) << 16);       \
            *reinterpret_cast<uint2*>(&Alds[offA1]) = wb;                       \
        }                                                                       \
        uint4 wc4;                                                              \
        wc4.x = (unsigned)f2bf(b0[0]) | ((unsigned)f2bf(b0[1]) << 16);          \
        wc4.y = (unsigned)f2bf(b0[2]) | ((unsigned)f2bf(b0[3]) << 16);          \
        wc4.z = (unsigned)f2bf(b0[4]) | ((unsigned)f2bf(b0[5]) << 16);          \
        wc4.w = (unsigned)f2bf(b0[6]) | ((unsigned)f2bf(b0[7]) << 16);          \
        *reinterpret_cast<uint4*>(&Blds[offB0]) = wc4;                          \
        if (hasB1) {                                                            \
            uint4 wd4;                                                          \
            wd4.x = (unsigned)f2bf(b1[0]) | ((unsigned)f2bf(b1[1]) << 16);      \
            wd4.y = (unsigned)f2bf(b1[2]) | ((unsigned)f2bf(b1[3]) << 16);      \
            wd4.z = (unsigned)f2bf(b1[4]) | ((unsigned)f2bf(b1[5]) << 16);      \
            wd4.w = (unsigned)f2bf(b1[6]) | ((unsigned)f2bf(b1[7]) << 16);      \
            *reinterpret_cast<uint4*>(&Blds[offB1]) = wd4;                      \
        }                                                                       \
    }

    LOAD_STAGE(0);

    for (int s = 0; s < NSTAGES; ++s) {
        __syncthreads();              // previous stage's LDS reads complete
        WRITE_STAGE();                // waits vmcnt on the prefetched loads
        __syncthreads();
        if (s + 1 < NSTAGES) LOAD_STAGE((s + 1) * BK);   // prefetch next stage

        v8s aa0 = *reinterpret_cast<const v8s*>(&Alds[aBase]);
        v8s aa1 = *reinterpret_cast<const v8s*>(&Alds[aBase + 16 * 8]);
        #pragma unroll
        for (int n = 0; n < 7; ++n) {
            v8s bb = *reinterpret_cast<const v8s*>(&Blds[bBase + n * 16 * 8]);
            acc[0][n] = __builtin_amdgcn_mfma_f32_16x16x32_bf16(aa0, bb, acc[0][n], 0, 0, 0);
            acc[1][n] = __builtin_amdgcn_mfma_f32_16x16x32_bf16(aa1, bb, acc[1][n], 0, 0, 0);
        }
    }

    // ---- epilogue: bias add + store ----
    // C/D layout (m89-verified): col = lane&15, row = (lane>>4)*4 + reg
    const float* bg = bias + (size_t)c * LOUT;
    #pragma unroll
    for (int n = 0; n < 7; ++n) {
        const int col = wc * 112 + n * 16 + (lane & 15);
        const float bv = bg[col];
        #pragma unroll
        for (int m = 0; m < 2; ++m) {
            const int row0 = wr * 32 + m * 16 + ((lane >> 4) << 2);
            #pragma unroll
            for (int j = 0; j < 4; ++j) {
                out[((size_t)(row0 + j) * CDIM + c) * LOUT + col] = acc[m][n][j] + bv;
            }
        }
    }
}

extern "C" void kernel_launch(void* const* d_in, const int* in_sizes, int n_in,
                              void* d_out, int out_size, void* d_ws, size_t ws_size,
                              hipStream_t stream) {
    const float* x  = (const float*)d_in[0];
    const float* W  = (const float*)d_in[1];
    const float* b  = (const float*)d_in[2];
    float* out      = (float*)d_out;
    grouped_linear_kernel<<<CDIM, NTHREADS, 0, stream>>>(x, W, b, out);
}

// Round 2
// 162.808 us; speedup vs baseline: 1.0433x; 1.0433x over previous
//
#include <hip/hip_runtime.h>

#define BDIM 128
#define CDIM 512
#define LIN  720
#define LOUT 336
#define BK   32
#define NSTAGES 23          // ceil(720/32): last stage half zero-padded
#define NTHREADS 768        // 12 waves: 4 (M) x 3 (N)
#define A_BUF (4 * BDIM * 8)   // ushorts per A stage buffer (4 k-octets)
#define B_BUF (4 * LOUT * 8)   // ushorts per B stage buffer

typedef short v8s __attribute__((ext_vector_type(8)));  // 8 bf16 (4 VGPR)
typedef float v4f __attribute__((ext_vector_type(4)));  // MFMA acc

__device__ __forceinline__ unsigned short f2bf(float f) {
    // round-to-nearest-even fp32 -> bf16 (finite inputs; no NaN path)
    unsigned int u = __builtin_bit_cast(unsigned int, f);
    u += 0x7fffu + ((u >> 16) & 1u);
    return (unsigned short)(u >> 16);
}
__device__ __forceinline__ unsigned pk2(float lo, float hi) {
    return (unsigned)f2bf(lo) | ((unsigned)f2bf(hi) << 16);
}

__global__ __launch_bounds__(NTHREADS, 3)
void grouped_linear_kernel(const float* __restrict__ x,
                           const float* __restrict__ W,
                           const float* __restrict__ bias,
                           float* __restrict__ out)
{
    const int c    = blockIdx.x;
    const int tid  = threadIdx.x;
    const int lane = tid & 63;
    const int wave = tid >> 6;
    const int wr   = wave / 3;   // 0..3 -> rows wr*32 .. +31
    const int wc   = wave % 3;   // 0..2 -> cols wc*112 .. +111

    // K-octet-subtiled, DOUBLE-BUFFERED LDS: [buf][oct][outer][8 bf16]
    __shared__ unsigned short Alds[2 * A_BUF];   // 16 KB
    __shared__ unsigned short Blds[2 * B_BUF];   // 43 KB

    const float* xg = x + (size_t)c * LIN;            // + row*CDIM*LIN + k
    const float* Wg = W + (size_t)c * LIN * LOUT;     // + k*LOUT + n

    // ---- staging tasks ----
    // A: 128 rows x 8 float4 k-chunks = 1024 tasks
    const int rowA0 = tid >> 3, kqA0 = tid & 7;
    const int tA1   = tid + NTHREADS;
    const int rowA1 = tA1 >> 3, kqA1 = tA1 & 7;
    const bool hasA1 = (tid < 1024 - NTHREADS);
    // B: 168 n-pairs x 4 k-octets = 672 tasks (dwordx2 loads, transpose on write)
    const bool hasB = (tid < 672);
    const int npB  = hasB ? tid % 168 : 0;
    const int octB = hasB ? tid / 168 : 0;
    const int n0B  = npB * 2;

    // LDS write offsets (ushort element index, within one buffer)
    const int offA0 = ((kqA0 >> 1) * BDIM + rowA0) * 8 + (kqA0 & 1) * 4;
    const int offA1 = ((kqA1 >> 1) * BDIM + rowA1) * 8 + (kqA1 & 1) * 4;
    const int offB  = (octB * LOUT + n0B) * 8;

    // fragment read bases: lane l -> outer = (l&15), k-octet = (l>>4)
    const int aBase = ((lane >> 4) * BDIM + wr * 32 + (lane & 15)) * 8;
    const int bBase = ((lane >> 4) * LOUT + wc * 112 + (lane & 15)) * 8;

    float a0[4], a1[4], bv[8][2];

    v4f acc[2][7];
    #pragma unroll
    for (int m = 0; m < 2; ++m)
        #pragma unroll
        for (int n = 0; n < 7; ++n)
            acc[m][n] = (v4f){0.f, 0.f, 0.f, 0.f};

#define LOAD_STAGE(KS)                                                          \
    {                                                                           \
        const int kA0 = (KS) + kqA0 * 4;                                        \
        if (kA0 < LIN) {                                                        \
            const float4 v = *reinterpret_cast<const float4*>(                  \
                xg + (size_t)rowA0 * (CDIM * LIN) + kA0);                       \
            a0[0] = v.x; a0[1] = v.y; a0[2] = v.z; a0[3] = v.w;                 \
        } else { a0[0] = a0[1] = a0[2] = a0[3] = 0.f; }                         \
        if (hasA1) {                                                            \
            const int kA1 = (KS) + kqA1 * 4;                                    \
            if (kA1 < LIN) {                                                    \
                const float4 v = *reinterpret_cast<const float4*>(              \
                    xg + (size_t)rowA1 * (CDIM * LIN) + kA1);                   \
                a1[0] = v.x; a1[1] = v.y; a1[2] = v.z; a1[3] = v.w;             \
            } else { a1[0] = a1[1] = a1[2] = a1[3] = 0.f; }                     \
        }                                                                       \
        if (hasB) {                                                             \
            const int kB = (KS) + octB * 8;                                     \
            if (kB < LIN) {                                                     \
                const float* p = Wg + (size_t)kB * LOUT + n0B;                  \
                _Pragma("unroll")                                               \
                for (int j = 0; j < 8; ++j) {                                   \
                    const float2 v = *reinterpret_cast<const float2*>(          \
                        p + (size_t)j * LOUT);                                  \
                    bv[j][0] = v.x; bv[j][1] = v.y;                             \
                }                                                               \
            } else {                                                            \
                _Pragma("unroll")                                               \
                for (int j = 0; j < 8; ++j) { bv[j][0] = 0.f; bv[j][1] = 0.f; } \
            }                                                                   \
        }                                                                       \
    }

#define WRITE_STAGE(BSEL)                                                       \
    {                                                                           \
        uint2 wa;                                                               \
        wa.x = pk2(a0[0], a0[1]); wa.y = pk2(a0[2], a0[3]);                     \
        *reinterpret_cast<uint2*>(&Alds[(BSEL) * A_BUF + offA0]) = wa;          \
        if (hasA1) {                                                            \
            uint2 wb;                                                           \
            wb.x = pk2(a1[0], a1[1]); wb.y = pk2(a1[2], a1[3]);                 \
            *reinterpret_cast<uint2*>(&Alds[(BSEL) * A_BUF + offA1]) = wb;      \
        }                                                                       \
        if (hasB) {                                                             \
            uint4 w0;                                                           \
            w0.x = pk2(bv[0][0], bv[1][0]); w0.y = pk2(bv[2][0], bv[3][0]);     \
            w0.z = pk2(bv[4][0], bv[5][0]); w0.w = pk2(bv[6][0], bv[7][0]);     \
            *reinterpret_cast<uint4*>(&Blds[(BSEL) * B_BUF + offB]) = w0;       \
            uint4 w1;                                                           \
            w1.x = pk2(bv[0][1], bv[1][1]); w1.y = pk2(bv[2][1], bv[3][1]);     \
            w1.z = pk2(bv[4][1], bv[5][1]); w1.w = pk2(bv[6][1], bv[7][1]);     \
            *reinterpret_cast<uint4*>(&Blds[(BSEL) * B_BUF + offB + 8]) = w1;   \
        }                                                                       \
    }

// Raw barrier: drain LDS ops (visibility) but NOT vmcnt -> prefetched global
// loads stay in flight across the barrier (T4-lite; avoids __syncthreads'
// forced vmcnt(0) drain). sched_barrier(0) pins ordering around it.
#define BLOCK_SYNC()                                                            \
    {                                                                           \
        asm volatile("s_waitcnt lgkmcnt(0)" ::: "memory");                      \
        __builtin_amdgcn_sched_barrier(0);                                      \
        __builtin_amdgcn_s_barrier();                                           \
        __builtin_amdgcn_sched_barrier(0);                                      \
    }

    // ---- prologue ----
    LOAD_STAGE(0);
    WRITE_STAGE(0);          // stage 0 -> buf 0 (vmcnt waits inserted by compiler)
    LOAD_STAGE(BK);          // stage 1 prefetch, in flight across barrier
    BLOCK_SYNC();

    // ---- main loop: one barrier per stage ----
    for (int s = 0; s < NSTAGES; ++s) {
        const int cur = s & 1;
        const int nxt = cur ^ 1;

        v8s aa0 = *reinterpret_cast<const v8s*>(&Alds[cur * A_BUF + aBase]);
        v8s aa1 = *reinterpret_cast<const v8s*>(&Alds[cur * A_BUF + aBase + 16 * 8]);
        #pragma unroll
        for (int n = 0; n < 7; ++n) {
            v8s bb = *reinterpret_cast<const v8s*>(
                &Blds[cur * B_BUF + bBase + n * 16 * 8]);
            acc[0][n] = __builtin_amdgcn_mfma_f32_16x16x32_bf16(aa0, bb, acc[0][n], 0, 0, 0);
            acc[1][n] = __builtin_amdgcn_mfma_f32_16x16x32_bf16(aa1, bb, acc[1][n], 0, 0, 0);
        }

        if (s + 1 < NSTAGES) WRITE_STAGE(nxt);          // consumes prefetched regs
        if (s + 2 < NSTAGES) LOAD_STAGE((s + 2) * BK);  // issue; crosses barrier
        BLOCK_SYNC();
    }

    // ---- epilogue: bias add + store ----
    // C/D layout (m89-verified): col = lane&15, row = (lane>>4)*4 + reg
    const float* bg = bias + (size_t)c * LOUT;
    #pragma unroll
    for (int n = 0; n < 7; ++n) {
        const int col = wc * 112 + n * 16 + (lane & 15);
        const float bvs = bg[col];
        #pragma unroll
        for (int m = 0; m < 2; ++m) {
            const int row0 = wr * 32 + m * 16 + ((lane >> 4) << 2);
            #pragma unroll
            for (int j = 0; j < 4; ++j) {
                out[((size_t)(row0 + j) * CDIM + c) * LOUT + col] = acc[m][n][j] + bvs;
            }
        }
    }
}

extern "C" void kernel_launch(void* const* d_in, const int* in_sizes, int n_in,
                              void* d_out, int out_size, void* d_ws, size_t ws_size,
                              hipStream_t stream) {
    const float* x  = (const float*)d_in[0];
    const float* W  = (const float*)d_in[1];
    const float* b  = (const float*)d_in[2];
    float* out      = (float*)d_out;
    grouped_linear_kernel<<<CDIM, NTHREADS, 0, stream>>>(x, W, b, out);
}